// Round 1
// baseline (52.599 us; speedup 1.0000x reference)
//
#include <hip/hip_runtime.h>

#define SCALE 0.35355339059327379f   // 8^-0.5
#define RSQRT2 0.70710678118654752f

// ws layout (float offsets)
#define QT_SZ   (68*68*64)           // padded transposed q image: [xp][yp][ic]
#define WT_SZ   (64*121*64)          // [oc][kh*11+kw][ic]
#define QT_OFF  0
#define KT_OFF  (QT_OFF + QT_SZ)
#define WQT_OFF (KT_OFF + QT_SZ)
#define WKT_OFF (WQT_OFF + WT_SZ)
#define QD_OFF  (WKT_OFF + WT_SZ)    // [oc][il] 64*64
#define KD_OFF  (QD_OFF + 4096)
#define VP_OFF  (KD_OFF + 4096)      // Vpart [yg][x][ch] 8*64*64

// ---------------- K1: 1x1 conv (q,k -> transposed padded imgs; v -> row-mean partials)
//                  + weight transposes for K2 ----------------
__global__ __launch_bounds__(192) void k1(const float* __restrict__ f,
                                          const float* __restrict__ w_qkv,
                                          const float* __restrict__ wq,
                                          const float* __restrict__ wk,
                                          float* __restrict__ ws)
{
    extern __shared__ float sm[];
    const int b = blockIdx.x, t = threadIdx.x;
    if (b < 512) {
        // compute block: x row, yg = group of 8 y's
        const int x = b >> 3, yg = b & 7;
        const int w = t >> 6, lane = t & 63;   // wave w: 0=q,1=k,2=v ; lane = oc
        float* fl = sm;           // [64][12] f slab (8 y per ic, padded pitch 12)
        float* wt = sm + 768;     // [64 ic][193] transposed w_qkv (pitch 193)
        if (t < 128) {
            const int ic = t >> 1, part = t & 1;
            *(float4*)&fl[ic*12 + part*4] =
                *(const float4*)(f + ic*4096 + x*64 + yg*8 + part*4);
        }
        #pragma unroll
        for (int j = 0; j < 16; ++j) {
            const int idx = t + 192*j;          // float4 index in [0,3072)
            float4 v = *(const float4*)(w_qkv + 4*idx);
            const int oc = idx >> 4;            // (4*idx)/64
            const int ic0 = (4*idx) & 63;
            wt[(ic0+0)*193 + oc] = v.x;
            wt[(ic0+1)*193 + oc] = v.y;
            wt[(ic0+2)*193 + oc] = v.z;
            wt[(ic0+3)*193 + oc] = v.w;
        }
        __syncthreads();
        float acc[8] = {0.f,0.f,0.f,0.f,0.f,0.f,0.f,0.f};
        #pragma unroll 8
        for (int ic = 0; ic < 64; ++ic) {
            const float wv = wt[ic*193 + w*64 + lane];
            const float4 a = *(const float4*)&fl[ic*12];
            const float4 c = *(const float4*)&fl[ic*12 + 4];
            acc[0] = fmaf(wv, a.x, acc[0]);
            acc[1] = fmaf(wv, a.y, acc[1]);
            acc[2] = fmaf(wv, a.z, acc[2]);
            acc[3] = fmaf(wv, a.w, acc[3]);
            acc[4] = fmaf(wv, c.x, acc[4]);
            acc[5] = fmaf(wv, c.y, acc[5]);
            acc[6] = fmaf(wv, c.z, acc[6]);
            acc[7] = fmaf(wv, c.w, acc[7]);
        }
        if (w < 2) {
            float* img = (w == 0) ? (ws + QT_OFF) : (ws + KT_OFF);
            const int rowb = (x + 2) * 68;
            #pragma unroll
            for (int j = 0; j < 8; ++j)
                img[(rowb + yg*8 + j + 2)*64 + lane] = acc[j];
            if (yg == 0) { img[(rowb+0)*64+lane] = 0.f; img[(rowb+1)*64+lane] = 0.f; }
            if (yg == 7) { img[(rowb+66)*64+lane] = 0.f; img[(rowb+67)*64+lane] = 0.f; }
            if (x < 4) {  // zero pad rows xp in {0,1,66,67}; yg splits the 68 cols
                const int xp = (x < 2) ? x : 64 + x;
                for (int yp = yg*9; yp < yg*9 + 9; ++yp)
                    if (yp < 68) img[(xp*68 + yp)*64 + lane] = 0.f;
            }
        } else {
            const float s = acc[0]+acc[1]+acc[2]+acc[3]+acc[4]+acc[5]+acc[6]+acc[7];
            (ws + VP_OFF)[(yg*64 + x)*64 + lane] = s * 0.015625f;   // /64 row-mean partial
        }
    } else {
        // weight transpose blocks: wq/wk [oc][ic][kh][kw] -> [oc][kh*11+kw][ic]
        const int b2 = b - 512;
        const int type = b2 >> 6, oc = b2 & 63;
        const float* wsrc = type ? wk : wq;
        float* wdst = type ? (ws + WKT_OFF) : (ws + WQT_OFF);
        float* wl = sm;   // 7744 floats, [ic][121]
        #pragma unroll
        for (int j = 0; j < 11; ++j) {
            const int idx = t + 192*j;
            if (idx < 1936)
                *(float4*)&wl[4*idx] = *(const float4*)(wsrc + oc*7744 + 4*idx);
        }
        __syncthreads();
        const int w = t >> 6, lane = t & 63;
        for (int j = 0; j < 41; ++j) {
            const int k = w + 3*j;
            if (k < 121)
                wdst[(oc*121 + k)*64 + lane] = wl[lane*121 + k];
        }
    }
}

// ---------------- K2: 11x11 stride-8 pad-2 conv + bias + exact GELU ----------------
// grid 256: (type, ox, ocg, oyh). lane = ic, waves = ocp (2 oc each), 4 oy per block-half.
__global__ __launch_bounds__(256) void k2(const float* __restrict__ ws_qT,
                                          const float* __restrict__ ws_kT,
                                          const float* __restrict__ ws_wqT,
                                          const float* __restrict__ ws_wkT,
                                          const float* __restrict__ bq,
                                          const float* __restrict__ bk,
                                          float* __restrict__ qd,
                                          float* __restrict__ kd)
{
    extern __shared__ float patch[];   // [64 ic][11 kh][37] pitch 407 (23 mod 32 -> 2-way only)
    const int b = blockIdx.x;
    const int type = b >> 7, ox = (b >> 4) & 7, ocg = (b >> 1) & 7, oyh = b & 1;
    const float* img  = type ? ws_kT : ws_qT;
    const float* wT   = type ? ws_wkT : ws_wqT;
    const float* bias = type ? bk : bq;
    float* outp = type ? kd : qd;
    const int t = threadIdx.x;
    const int ocp = t >> 6, lane = t & 63;

    // stage: patch[ic][kh][yl] = img[ox*8+kh][oyh*32+yl][ic], yl in [0,35)
    for (int kh = 0; kh < 11; ++kh) {
        const int xrow = (ox*8 + kh) * 68;
        for (int yl = ocp; yl < 35; yl += 4)
            patch[lane*407 + kh*37 + yl] = img[(xrow + oyh*32 + yl)*64 + lane];
    }
    __syncthreads();

    const int oc0 = ocg*8 + ocp*2, oc1 = oc0 + 1;
    const float* wb0 = wT + oc0*121*64 + lane;
    const float* wb1 = wT + oc1*121*64 + lane;
    float acc0[4] = {0.f,0.f,0.f,0.f};
    float acc1[4] = {0.f,0.f,0.f,0.f};
    for (int kh = 0; kh < 11; ++kh) {
        const float* prow = &patch[lane*407 + kh*37];
        #pragma unroll
        for (int kw = 0; kw < 11; ++kw) {
            const float w0 = wb0[(kh*11 + kw)*64];
            const float w1 = wb1[(kh*11 + kw)*64];
            #pragma unroll
            for (int oy = 0; oy < 4; ++oy) {
                const float v = prow[kw + oy*8];
                acc0[oy] = fmaf(w0, v, acc0[oy]);
                acc1[oy] = fmaf(w1, v, acc1[oy]);
            }
        }
    }
    #pragma unroll
    for (int j = 0; j < 4; ++j) {
        float v0 = acc0[j], v1 = acc1[j];
        #pragma unroll
        for (int m = 1; m < 64; m <<= 1) {
            v0 += __shfl_xor(v0, m, 64);
            v1 += __shfl_xor(v1, m, 64);
        }
        acc0[j] = v0; acc1[j] = v1;
    }
    if (lane == 0) {
        const float b0 = bias[oc0], b1 = bias[oc1];
        #pragma unroll
        for (int j = 0; j < 4; ++j) {
            const int il = ox*8 + oyh*4 + j;
            const float v0 = acc0[j] + b0;
            const float v1 = acc1[j] + b1;
            outp[oc0*64 + il] = 0.5f*v0*(1.0f + erff(v0*RSQRT2));
            outp[oc1*64 + il] = 0.5f*v1*(1.0f + erff(v1*RSQRT2));
        }
    }
}

// ---------------- K3: dots + softmax + PV + broadcast store ----------------
// grid 64 (x = image row), 512 threads: wave = head h, lane = jl.
__global__ __launch_bounds__(512) void k3(const float* __restrict__ qd,
                                          const float* __restrict__ kd,
                                          const float* __restrict__ Vpart,
                                          float* __restrict__ out)
{
    __shared__ float vrow[64*65];   // [jl][ch], pitch 65
    const int x = blockIdx.x, t = threadIdx.x;
    {
        const int jl = t >> 3, ch0 = (t & 7) * 8;
        float s[8] = {0.f,0.f,0.f,0.f,0.f,0.f,0.f,0.f};
        for (int yg = 0; yg < 8; ++yg) {
            const float* p = Vpart + (yg*64 + jl)*64 + ch0;
            const float4 a = *(const float4*)p;
            const float4 c = *(const float4*)(p + 4);
            s[0]+=a.x; s[1]+=a.y; s[2]+=a.z; s[3]+=a.w;
            s[4]+=c.x; s[5]+=c.y; s[6]+=c.z; s[7]+=c.w;
        }
        #pragma unroll
        for (int e = 0; e < 8; ++e) vrow[jl*65 + ch0 + e] = s[e];
    }
    __syncthreads();
    const int h = t >> 6, lane = t & 63;
    float d = 0.f;
    #pragma unroll
    for (int c = 0; c < 8; ++c)
        d = fmaf(qd[(h*8 + c)*64 + x], kd[(h*8 + c)*64 + lane], d);
    d *= SCALE;
    float m = d;
    #pragma unroll
    for (int mm = 1; mm < 64; mm <<= 1) m = fmaxf(m, __shfl_xor(m, mm, 64));
    const float e = __expf(d - m);
    float ssum = e;
    #pragma unroll
    for (int mm = 1; mm < 64; mm <<= 1) ssum += __shfl_xor(ssum, mm, 64);
    const float p = e / ssum;
    #pragma unroll
    for (int c = 0; c < 8; ++c) {
        float r = p * vrow[lane*65 + h*8 + c];
        #pragma unroll
        for (int mm = 1; mm < 64; mm <<= 1) r += __shfl_xor(r, mm, 64);
        out[(h*8 + c)*4096 + x*64 + lane] = r;
    }
}

extern "C" void kernel_launch(void* const* d_in, const int* in_sizes, int n_in,
                              void* d_out, int out_size, void* d_ws, size_t ws_size,
                              hipStream_t stream) {
    const float* f     = (const float*)d_in[0];
    const float* w_qkv = (const float*)d_in[1];
    const float* wq    = (const float*)d_in[2];
    const float* bq    = (const float*)d_in[3];
    const float* wk    = (const float*)d_in[4];
    const float* bk    = (const float*)d_in[5];
    float* out = (float*)d_out;
    float* ws  = (float*)d_ws;

    k1<<<640, 192, 13120*4, stream>>>(f, w_qkv, wq, wk, ws);
    k2<<<256, 256, 26048*4, stream>>>(ws + QT_OFF, ws + KT_OFF,
                                      ws + WQT_OFF, ws + WKT_OFF,
                                      bq, bk, ws + QD_OFF, ws + KD_OFF);
    k3<<<64, 512, 0, stream>>>(ws + QD_OFF, ws + KD_OFF, ws + VP_OFF, out);
}

// Round 2
// 52.052 us; speedup vs baseline: 1.0105x; 1.0105x over previous
//
#include <hip/hip_runtime.h>

#define SCALE 0.35355339059327379f   // 8^-0.5
#define RSQRT2 0.70710678118654752f

// ws layout (float offsets)
#define QT_SZ   (68*68*64)           // padded transposed q image: [xp][yp][ic]
#define WT_SZ   (64*121*64)          // [oc][kh*11+kw][ic]
#define QT_OFF  0
#define KT_OFF  (QT_OFF + QT_SZ)
#define WQT_OFF (KT_OFF + QT_SZ)
#define WKT_OFF (WQT_OFF + WT_SZ)
#define QD_OFF  (WKT_OFF + WT_SZ)    // [oc][il] 64*64
#define KD_OFF  (QD_OFF + 4096)
#define VP_OFF  (KD_OFF + 4096)      // Vpart [yg][x][ch] 8*64*64

// ---------------- K1: 1x1 conv (q,k -> transposed padded imgs; v -> row-mean partials)
//                  + weight transposes for K2 ----------------
__global__ __launch_bounds__(192) void k1(const float* __restrict__ f,
                                          const float* __restrict__ w_qkv,
                                          const float* __restrict__ wq,
                                          const float* __restrict__ wk,
                                          float* __restrict__ ws)
{
    extern __shared__ float sm[];
    const int b = blockIdx.x, t = threadIdx.x;
    if (b < 512) {
        // compute block: x row, yg = group of 8 y's
        const int x = b >> 3, yg = b & 7;
        const int w = t >> 6, lane = t & 63;   // wave w: 0=q,1=k,2=v ; lane = oc
        float* fl = sm;           // [64][12] f slab (8 y per ic, padded pitch 12)
        float* wt = sm + 768;     // [64 ic][193] transposed w_qkv (pitch 193)
        if (t < 128) {
            const int ic = t >> 1, part = t & 1;
            *(float4*)&fl[ic*12 + part*4] =
                *(const float4*)(f + ic*4096 + x*64 + yg*8 + part*4);
        }
        #pragma unroll
        for (int j = 0; j < 16; ++j) {
            const int idx = t + 192*j;          // float4 index in [0,3072)
            float4 v = *(const float4*)(w_qkv + 4*idx);
            const int oc = idx >> 4;            // (4*idx)/64
            const int ic0 = (4*idx) & 63;
            wt[(ic0+0)*193 + oc] = v.x;
            wt[(ic0+1)*193 + oc] = v.y;
            wt[(ic0+2)*193 + oc] = v.z;
            wt[(ic0+3)*193 + oc] = v.w;
        }
        __syncthreads();
        float acc[8] = {0.f,0.f,0.f,0.f,0.f,0.f,0.f,0.f};
        #pragma unroll 8
        for (int ic = 0; ic < 64; ++ic) {
            const float wv = wt[ic*193 + w*64 + lane];
            const float4 a = *(const float4*)&fl[ic*12];
            const float4 c = *(const float4*)&fl[ic*12 + 4];
            acc[0] = fmaf(wv, a.x, acc[0]);
            acc[1] = fmaf(wv, a.y, acc[1]);
            acc[2] = fmaf(wv, a.z, acc[2]);
            acc[3] = fmaf(wv, a.w, acc[3]);
            acc[4] = fmaf(wv, c.x, acc[4]);
            acc[5] = fmaf(wv, c.y, acc[5]);
            acc[6] = fmaf(wv, c.z, acc[6]);
            acc[7] = fmaf(wv, c.w, acc[7]);
        }
        if (w < 2) {
            float* img = (w == 0) ? (ws + QT_OFF) : (ws + KT_OFF);
            const int rowb = (x + 2) * 68;
            #pragma unroll
            for (int j = 0; j < 8; ++j)
                img[(rowb + yg*8 + j + 2)*64 + lane] = acc[j];
            if (yg == 0) { img[(rowb+0)*64+lane] = 0.f; img[(rowb+1)*64+lane] = 0.f; }
            if (yg == 7) { img[(rowb+66)*64+lane] = 0.f; img[(rowb+67)*64+lane] = 0.f; }
            if (x < 4) {  // zero pad rows xp in {0,1,66,67}; yg splits the 68 cols
                const int xp = (x < 2) ? x : 64 + x;
                for (int yp = yg*9; yp < yg*9 + 9; ++yp)
                    if (yp < 68) img[(xp*68 + yp)*64 + lane] = 0.f;
            }
        } else {
            const float s = acc[0]+acc[1]+acc[2]+acc[3]+acc[4]+acc[5]+acc[6]+acc[7];
            (ws + VP_OFF)[(yg*64 + x)*64 + lane] = s * 0.015625f;   // /64 row-mean partial
        }
    } else {
        // weight transpose blocks: wq/wk [oc][ic][kh][kw] -> [oc][kh*11+kw][ic]
        const int b2 = b - 512;
        const int type = b2 >> 6, oc = b2 & 63;
        const float* wsrc = type ? wk : wq;
        float* wdst = type ? (ws + WKT_OFF) : (ws + WQT_OFF);
        float* wl = sm;   // 7744 floats, [ic][121]
        #pragma unroll
        for (int j = 0; j < 11; ++j) {
            const int idx = t + 192*j;
            if (idx < 1936)
                *(float4*)&wl[4*idx] = *(const float4*)(wsrc + oc*7744 + 4*idx);
        }
        __syncthreads();
        const int w = t >> 6, lane = t & 63;
        for (int j = 0; j < 41; ++j) {
            const int k = w + 3*j;
            if (k < 121)
                wdst[(oc*121 + k)*64 + lane] = wl[lane*121 + k];
        }
    }
}

// ---------------- K2: 11x11 stride-8 pad-2 conv + bias + exact GELU ----------------
// grid 256: (type, ox, ocg, oyh). lane = ic, waves = ocp (2 oc each), 4 oy per block-half.
// kh processed in two chunks (6+5) so the patch fits in 57 KB LDS -> 2 blocks/CU,
// 8 waves/CU to hide the L2/L3 weight-stream latency.
__global__ __launch_bounds__(256) void k2(const float* __restrict__ ws_qT,
                                          const float* __restrict__ ws_kT,
                                          const float* __restrict__ ws_wqT,
                                          const float* __restrict__ ws_wkT,
                                          const float* __restrict__ bq,
                                          const float* __restrict__ bk,
                                          float* __restrict__ qd,
                                          float* __restrict__ kd)
{
    __shared__ float patch[64*223];   // [64 ic][pitch 223 = 6 kh * 37 + pad] (223 odd -> 2-way only)
    const int b = blockIdx.x;
    const int type = b >> 7, ox = (b >> 4) & 7, ocg = (b >> 1) & 7, oyh = b & 1;
    const float* img  = type ? ws_kT : ws_qT;
    const float* wT   = type ? ws_wkT : ws_wqT;
    const float* bias = type ? bk : bq;
    float* outp = type ? kd : qd;
    const int t = threadIdx.x;
    const int ocp = t >> 6, lane = t & 63;

    const int oc0 = ocg*8 + ocp*2, oc1 = oc0 + 1;
    const float* wb0 = wT + oc0*121*64 + lane;
    const float* wb1 = wT + oc1*121*64 + lane;
    float acc0[4] = {0.f,0.f,0.f,0.f};
    float acc1[4] = {0.f,0.f,0.f,0.f};

    #pragma unroll
    for (int chunk = 0; chunk < 2; ++chunk) {
        const int kh0 = chunk ? 6 : 0;
        const int nkh = chunk ? 5 : 6;
        if (chunk) __syncthreads();   // all waves done computing on previous patch
        // stage: patch[ic][kh][yl] = img[ox*8+kh0+kh][oyh*32+yl][ic], yl in [0,35)
        for (int kh = 0; kh < nkh; ++kh) {
            const int xrow = (ox*8 + kh0 + kh) * 68;
            for (int yl = ocp; yl < 35; yl += 4)
                patch[lane*223 + kh*37 + yl] = img[(xrow + oyh*32 + yl)*64 + lane];
        }
        __syncthreads();
        for (int kh = 0; kh < nkh; ++kh) {
            const float* prow = &patch[lane*223 + kh*37];
            const int khg = kh0 + kh;
            #pragma unroll
            for (int kw = 0; kw < 11; ++kw) {
                const float w0 = wb0[(khg*11 + kw)*64];
                const float w1 = wb1[(khg*11 + kw)*64];
                #pragma unroll
                for (int oy = 0; oy < 4; ++oy) {
                    const float v = prow[kw + oy*8];
                    acc0[oy] = fmaf(w0, v, acc0[oy]);
                    acc1[oy] = fmaf(w1, v, acc1[oy]);
                }
            }
        }
    }

    #pragma unroll
    for (int j = 0; j < 4; ++j) {
        float v0 = acc0[j], v1 = acc1[j];
        #pragma unroll
        for (int m = 1; m < 64; m <<= 1) {
            v0 += __shfl_xor(v0, m, 64);
            v1 += __shfl_xor(v1, m, 64);
        }
        acc0[j] = v0; acc1[j] = v1;
    }
    if (lane == 0) {
        const float b0 = bias[oc0], b1 = bias[oc1];
        #pragma unroll
        for (int j = 0; j < 4; ++j) {
            const int il = ox*8 + oyh*4 + j;
            const float v0 = acc0[j] + b0;
            const float v1 = acc1[j] + b1;
            outp[oc0*64 + il] = 0.5f*v0*(1.0f + erff(v0*RSQRT2));
            outp[oc1*64 + il] = 0.5f*v1*(1.0f + erff(v1*RSQRT2));
        }
    }
}

// ---------------- K3: dots + softmax + PV + broadcast store ----------------
// grid 64 (x = image row), 512 threads: wave = head h, lane = jl.
__global__ __launch_bounds__(512) void k3(const float* __restrict__ qd,
                                          const float* __restrict__ kd,
                                          const float* __restrict__ Vpart,
                                          float* __restrict__ out)
{
    __shared__ float vrow[64*65];   // [jl][ch], pitch 65
    const int x = blockIdx.x, t = threadIdx.x;
    {
        const int jl = t >> 3, ch0 = (t & 7) * 8;
        float s[8] = {0.f,0.f,0.f,0.f,0.f,0.f,0.f,0.f};
        for (int yg = 0; yg < 8; ++yg) {
            const float* p = Vpart + (yg*64 + jl)*64 + ch0;
            const float4 a = *(const float4*)p;
            const float4 c = *(const float4*)(p + 4);
            s[0]+=a.x; s[1]+=a.y; s[2]+=a.z; s[3]+=a.w;
            s[4]+=c.x; s[5]+=c.y; s[6]+=c.z; s[7]+=c.w;
        }
        #pragma unroll
        for (int e = 0; e < 8; ++e) vrow[jl*65 + ch0 + e] = s[e];
    }
    __syncthreads();
    const int h = t >> 6, lane = t & 63;
    float d = 0.f;
    #pragma unroll
    for (int c = 0; c < 8; ++c)
        d = fmaf(qd[(h*8 + c)*64 + x], kd[(h*8 + c)*64 + lane], d);
    d *= SCALE;
    float m = d;
    #pragma unroll
    for (int mm = 1; mm < 64; mm <<= 1) m = fmaxf(m, __shfl_xor(m, mm, 64));
    const float e = __expf(d - m);
    float ssum = e;
    #pragma unroll
    for (int mm = 1; mm < 64; mm <<= 1) ssum += __shfl_xor(ssum, mm, 64);
    const float p = e / ssum;
    #pragma unroll
    for (int c = 0; c < 8; ++c) {
        float r = p * vrow[lane*65 + h*8 + c];
        #pragma unroll
        for (int mm = 1; mm < 64; mm <<= 1) r += __shfl_xor(r, mm, 64);
        out[(h*8 + c)*4096 + x*64 + lane] = r;
    }
}

extern "C" void kernel_launch(void* const* d_in, const int* in_sizes, int n_in,
                              void* d_out, int out_size, void* d_ws, size_t ws_size,
                              hipStream_t stream) {
    const float* f     = (const float*)d_in[0];
    const float* w_qkv = (const float*)d_in[1];
    const float* wq    = (const float*)d_in[2];
    const float* bq    = (const float*)d_in[3];
    const float* wk    = (const float*)d_in[4];
    const float* bk    = (const float*)d_in[5];
    float* out = (float*)d_out;
    float* ws  = (float*)d_ws;

    k1<<<640, 192, 13120*4, stream>>>(f, w_qkv, wq, wk, ws);
    k2<<<256, 256, 0, stream>>>(ws + QT_OFF, ws + KT_OFF,
                                ws + WQT_OFF, ws + WKT_OFF,
                                bq, bk, ws + QD_OFF, ws + KD_OFF);
    k3<<<64, 512, 0, stream>>>(ws + QD_OFF, ws + KD_OFF, ws + VP_OFF, out);
}